// Round 9
// baseline (191.216 us; speedup 1.0000x reference)
//
#include <hip/hip_runtime.h>
#include <math.h>

#define B_ 8
#define T_ 1024
#define C_ 768
#define H_ 12
#define D_ 64

typedef __bf16 bf16x8 __attribute__((ext_vector_type(8)));
typedef float  f32x4  __attribute__((ext_vector_type(4)));
typedef unsigned short us8 __attribute__((ext_vector_type(8)));
typedef unsigned int   u32x4v __attribute__((ext_vector_type(4)));

typedef __attribute__((address_space(3))) void lds_void;
typedef __attribute__((address_space(1))) const void glb_void;

#define KSC 0.18033688011112043f   // 0.125 * log2(e)

__device__ __forceinline__ unsigned short f2bf(float f) {
    unsigned int u = __float_as_uint(f);
    u += 0x7fffu + ((u >> 16) & 1u);
    return (unsigned short)(u >> 16);
}

// ---------------- prep: weight transposes (+Q scale) + bias -----------------
__global__ __launch_bounds__(256)
void prep_w(const float* __restrict__ w_qkv, const float* __restrict__ b_qkv,
            const float* __restrict__ w_proj,
            unsigned short* __restrict__ wqT, unsigned short* __restrict__ wpT,
            float* __restrict__ bqs) {
    __shared__ unsigned short Ts[64][65];
    const int id  = blockIdx.x;
    const int tid = threadIdx.x;
    if (id == 576) {
        for (int i = tid; i < 3 * C_; i += 256)
            bqs[i] = b_qkv[i] * (i < C_ ? KSC : 1.f);
        return;
    }
    const float* W; unsigned short* Wt; int N, nlim, t2;
    if (id < 432) { t2 = id;       W = w_qkv;  Wt = wqT; N = 3 * C_; nlim = C_; }
    else          { t2 = id - 432; W = w_proj; Wt = wpT; N = C_;     nlim = 0;  }
    const int ntiles = N / 64;
    const int n0 = (t2 % ntiles) * 64, k0 = (t2 / ntiles) * 64;
    for (int i = tid; i < 4096; i += 256) {
        int n = i & 63, k = i >> 6;
        float sc = (n0 + n < nlim) ? KSC : 1.f;
        Ts[n][k] = f2bf(W[(size_t)(k0 + k) * N + n0 + n] * sc);
    }
    __syncthreads();
    for (int i = tid; i < 4096; i += 256) {
        int k = i & 63, n = i >> 6;
        Wt[(size_t)(n0 + n) * 768 + k0 + k] = Ts[n][k];
    }
}

// ---------------- single-barrier dbuf bf16 MFMA GEMM ------------------------
// TM x 128 tile, BK=32, both A and B double-buffered (TM=128: 32 KB LDS ->
// 5 blocks/CU). One __syncthreads per round: barrier at top of round r
// separates round r-1 reads from round r+1 writes. Per round: load A(r+1)
// regs -> issue B(r+1) global_load_lds -> compute r -> ds_write A(r+1)
// (vmcnt waits only A; B drains at next barrier, a full round later).
// LDS cells (16B): logical (row,kc) at linear row*4 + (kc ^ (row&3)):
// staging conflict-free, frag ds_read_b128 2 lanes/bank-set (free).
// blockIdx.x = M -> same-m blocks share XCD -> A L2-resident.
template<int TM, int A_FP32, int OUT_BF16>
__global__ __launch_bounds__(256, 4)
void gemm_pipe(const float* __restrict__ Af, const unsigned short* __restrict__ A16,
               const unsigned short* __restrict__ Bt, const float* __restrict__ bias,
               void* __restrict__ Cout, int M, int N, int K) {
    const int PA = TM / 64;     // A cells per thread (cells = TM*4)
    const int MI = TM / 32;     // m-frags per wave
    __shared__ __align__(16) unsigned short As[2][TM * 32];
    __shared__ __align__(16) unsigned short Bs[2][4096];

    const int tid  = threadIdx.x;
    const int lane = tid & 63;
    const int c    = lane & 15;
    const int quad = lane >> 4;
    const int wave = tid >> 6;
    const int wm   = (wave >> 1) * (TM / 2);
    const int wn   = (wave & 1) * 64;
    const int bm   = blockIdx.x * TM;
    const int bn   = blockIdx.y * 128;

    // A staging: thread owns linear cells Lp; logical kc = (Lp ^ row) & 3
    const float*          aF[PA];
    const unsigned short* aH[PA];
    int wAddr[PA];
#pragma unroll
    for (int p = 0; p < PA; p++) {
        const int Lp = p * 256 + tid;
        const int r  = Lp >> 2;
        const int kc = (Lp ^ r) & 3;
        if (A_FP32) aF[p] = Af  + (size_t)(bm + r) * K + kc * 8;
        else        aH[p] = A16 + (size_t)(bm + r) * K + kc * 8;
        wAddr[p] = Lp * 8;
    }
    // B staging via global_load_lds (lane-contiguous dest), pre-swizzled src
    const unsigned short* bS[2];
#pragma unroll
    for (int p = 0; p < 2; p++) {
        const int Lp = p * 256 + tid;
        const int r  = Lp >> 2;
        const int kc = (Lp ^ r) & 3;
        bS[p] = Bt + (size_t)(bn + r) * K + kc * 8;
    }
    const int wb = (tid & 0xC0) * 8;

    int aoff[MI], boff[4];
#pragma unroll
    for (int i = 0; i < MI; i++)
        aoff[i] = ((wm + i * 16 + c) * 4 + (quad ^ (c & 3))) * 8;
#pragma unroll
    for (int j = 0; j < 4; j++)
        boff[j] = ((wn + j * 16 + c) * 4 + (quad ^ (c & 3))) * 8;

    float4 a0[PA], a1[PA];
    us8    aR[PA];
    f32x4 acc[MI][4];
#pragma unroll
    for (int i = 0; i < MI; i++)
#pragma unroll
        for (int j = 0; j < 4; j++) acc[i][j] = (f32x4){0.f, 0.f, 0.f, 0.f};

    // prologue: stage round 0
#pragma unroll
    for (int p = 0; p < PA; p++) {
        if (A_FP32) { a0[p] = *(const float4*)aF[p]; a1[p] = *(const float4*)(aF[p] + 4); aF[p] += 32; }
        else        { aR[p] = *(const us8*)aH[p]; aH[p] += 32; }
    }
#pragma unroll
    for (int p = 0; p < 2; p++) {
        __builtin_amdgcn_global_load_lds((glb_void*)bS[p],
            (lds_void*)(&Bs[0][0] + p * 2048 + wb), 16, 0, 0);
        bS[p] += 32;
    }
#pragma unroll
    for (int p = 0; p < PA; p++) {
        us8 w;
        if (A_FP32) {
            w[0] = f2bf(a0[p].x); w[1] = f2bf(a0[p].y);
            w[2] = f2bf(a0[p].z); w[3] = f2bf(a0[p].w);
            w[4] = f2bf(a1[p].x); w[5] = f2bf(a1[p].y);
            w[6] = f2bf(a1[p].z); w[7] = f2bf(a1[p].w);
        } else w = aR[p];
        *(us8*)&As[0][wAddr[p]] = w;
    }

    const int R = K >> 5;
    for (int r = 0; r < R; r++) {
        __syncthreads();   // staging for round r visible; drains B(r) loads
        const int bb = r & 1, nb = bb ^ 1;
        if (r + 1 < R) {   // A regs first (so ds_write won't drain B's vmcnt)
#pragma unroll
            for (int p = 0; p < PA; p++) {
                if (A_FP32) { a0[p] = *(const float4*)aF[p]; a1[p] = *(const float4*)(aF[p] + 4); aF[p] += 32; }
                else        { aR[p] = *(const us8*)aH[p]; aH[p] += 32; }
            }
#pragma unroll
            for (int p = 0; p < 2; p++) {
                __builtin_amdgcn_global_load_lds((glb_void*)bS[p],
                    (lds_void*)(&Bs[nb][0] + p * 2048 + wb), 16, 0, 0);
                bS[p] += 32;
            }
        }

        bf16x8 af[MI], bfr[4];
#pragma unroll
        for (int i = 0; i < MI; i++)
            af[i] = __builtin_bit_cast(bf16x8, *(const us8*)&As[bb][aoff[i]]);
#pragma unroll
        for (int j = 0; j < 4; j++)
            bfr[j] = __builtin_bit_cast(bf16x8, *(const us8*)&Bs[bb][boff[j]]);
#pragma unroll
        for (int i = 0; i < MI; i++)
#pragma unroll
            for (int j = 0; j < 4; j++)
                acc[i][j] = __builtin_amdgcn_mfma_f32_16x16x32_bf16(af[i], bfr[j], acc[i][j], 0, 0, 0);

        if (r + 1 < R) {
#pragma unroll
            for (int p = 0; p < PA; p++) {
                us8 w;
                if (A_FP32) {
                    w[0] = f2bf(a0[p].x); w[1] = f2bf(a0[p].y);
                    w[2] = f2bf(a0[p].z); w[3] = f2bf(a0[p].w);
                    w[4] = f2bf(a1[p].x); w[5] = f2bf(a1[p].y);
                    w[6] = f2bf(a1[p].z); w[7] = f2bf(a1[p].w);
                } else w = aR[p];
                *(us8*)&As[nb][wAddr[p]] = w;
            }
        }
    }

    float bs[4];
#pragma unroll
    for (int j = 0; j < 4; j++) bs[j] = bias[bn + wn + j * 16 + c];
#pragma unroll
    for (int i = 0; i < MI; i++) {
        const int gm = bm + wm + i * 16 + quad * 4;
#pragma unroll
        for (int r = 0; r < 4; r++) {
            const size_t ro = (size_t)(gm + r) * N;
#pragma unroll
            for (int j = 0; j < 4; j++) {
                const float v = acc[i][j][r] + bs[j];
                const int gn = bn + wn + j * 16 + c;
                if (OUT_BF16) ((unsigned short*)Cout)[ro + gn] = f2bf(v);
                else          ((float*)Cout)[ro + gn] = v;
            }
        }
    }
}

// key k -> permuted LDS row, chosen so S^T output lands in PV A-frag layout
__device__ __forceinline__ int sigmaK(int k) {
    return 16 * (2 * (k >> 5) + ((k >> 2) & 1)) + 4 * ((k >> 3) & 3) + (k & 3);
}

// ---------------- flash attention: S^T trick, in-register P -----------------
__global__ __launch_bounds__(256, 3)
void attn_mfma(const unsigned short* __restrict__ qkv, unsigned short* __restrict__ y) {
    __shared__ __align__(16) unsigned short Ks[64 * 72];
    __shared__ __align__(16) unsigned int   Vt[64 * 36];

    const int tid  = threadIdx.x;
    const int wave = tid >> 6;
    const int lane = tid & 63;
    const int c    = lane & 15;
    const int quad = lane >> 4;

    const int id = blockIdx.x;
    const int p  = (id >> 3) & 7;
    const int bh = (id >> 6) * 8 + (id & 7);
    const int b  = bh / H_;
    const int h  = bh - b * H_;

    const int qts[2] = {p, 15 - p};
    const int q0s[2] = {p * 64, (15 - p) * 64};

    const int RS = 3 * C_;
    const unsigned short* kbase = qkv + (size_t)b * T_ * RS + C_ + h * D_;
    const unsigned short* vbase = qkv + (size_t)b * T_ * RS + 2 * C_ + h * D_;

    const u32x4v onesu = {0x3F803F80u, 0x3F803F80u, 0x3F803F80u, 0x3F803F80u};
    const bf16x8 onesf = __builtin_bit_cast(bf16x8, onesu);

    bf16x8 qf[2][2];
#pragma unroll
    for (int t = 0; t < 2; t++) {
        const unsigned short* qrow =
            qkv + ((size_t)(b * T_ + q0s[t] + wave * 16 + c)) * RS + h * D_ + quad * 8;
        qf[t][0] = __builtin_bit_cast(bf16x8, *(const us8*)qrow);
        qf[t][1] = __builtin_bit_cast(bf16x8, *(const us8*)(qrow + 32));
    }

    const int kr0 = tid >> 3, kc0 = tid & 7;
    const int sK0 = sigmaK(kr0) * 72 + kc0 * 8;
    const int sK1 = sigmaK(kr0 + 32) * 72 + kc0 * 8;
    const int dg  = tid >> 4, kp0 = tid & 15;

    us8 kA, kB;
    ushort4 vA0, vB0, vA1, vB1;
    {
        kA = *(const us8*)(kbase + (size_t)kr0 * RS + kc0 * 8);
        kB = *(const us8*)(kbase + (size_t)(kr0 + 32) * RS + kc0 * 8);
        const unsigned short* p0 = vbase + (size_t)(2 * kp0) * RS + dg * 4;
        vA0 = *(const ushort4*)p0;  vB0 = *(const ushort4*)(p0 + RS);
        const unsigned short* p1 = vbase + (size_t)(2 * (kp0 + 16)) * RS + dg * 4;
        vA1 = *(const ushort4*)p1;  vB1 = *(const ushort4*)(p1 + RS);
    }

    f32x4 Oa[2][4];
    f32x4 Ol[2];
#pragma unroll
    for (int t = 0; t < 2; t++) {
        Ol[t] = (f32x4){0.f, 0.f, 0.f, 0.f};
#pragma unroll
        for (int d = 0; d < 4; d++) Oa[t][d] = (f32x4){0.f, 0.f, 0.f, 0.f};
    }

    const int ktEnd = qts[1];
    for (int kt = 0; kt <= ktEnd; kt++) {
        __syncthreads();
        *(us8*)&Ks[sK0] = kA;
        *(us8*)&Ks[sK1] = kB;
        {
            unsigned int* v0 = &Vt[(dg * 4) * 36 + kp0];
            v0[0]   = vA0.x | ((unsigned)vB0.x << 16);
            v0[36]  = vA0.y | ((unsigned)vB0.y << 16);
            v0[72]  = vA0.z | ((unsigned)vB0.z << 16);
            v0[108] = vA0.w | ((unsigned)vB0.w << 16);
            unsigned int* v1 = v0 + 16;
            v1[0]   = vA1.x | ((unsigned)vB1.x << 16);
            v1[36]  = vA1.y | ((unsigned)vB1.y << 16);
            v1[72]  = vA1.z | ((unsigned)vB1.z << 16);
            v1[108] = vA1.w | ((unsigned)vB1.w << 16);
        }
        __syncthreads();

        if (kt < ktEnd) {
            const unsigned short* kp = kbase + (size_t)((kt + 1) * 64) * RS;
            kA = *(const us8*)(kp + (size_t)kr0 * RS + kc0 * 8);
            kB = *(const us8*)(kp + (size_t)(kr0 + 32) * RS + kc0 * 8);
            const unsigned short* vp = vbase + (size_t)((kt + 1) * 64) * RS;
            const unsigned short* p0 = vp + (size_t)(2 * kp0) * RS + dg * 4;
            vA0 = *(const ushort4*)p0;  vB0 = *(const ushort4*)(p0 + RS);
            const unsigned short* p1 = vp + (size_t)(2 * (kp0 + 16)) * RS + dg * 4;
            vA1 = *(const ushort4*)p1;  vB1 = *(const ushort4*)(p1 + RS);
        }

        bf16x8 kf[4][2];
#pragma unroll
        for (int nb = 0; nb < 4; nb++) {
#pragma unroll
            for (int ks = 0; ks < 2; ks++)
                kf[nb][ks] = __builtin_bit_cast(bf16x8,
                    *(const us8*)&Ks[(nb * 16 + c) * 72 + quad * 8 + ks * 32]);
        }

#pragma unroll
        for (int t = 0; t < 2; t++) {
            if (kt > qts[t]) continue;
            const bool diag = (kt == qts[t]);
            const bool doHi = !diag || (wave >= 2);
            const int nbmax = diag ? ((wave >= 2) ? 3 : 1) : 3;

            f32x4 sv[4];
#pragma unroll
            for (int nb = 0; nb < 4; nb++) {
                if (nb <= nbmax) {
                    f32x4 z = (f32x4){0.f, 0.f, 0.f, 0.f};
                    z = __builtin_amdgcn_mfma_f32_16x16x32_bf16(kf[nb][0], qf[t][0], z, 0, 0, 0);
                    sv[nb] = __builtin_amdgcn_mfma_f32_16x16x32_bf16(kf[nb][1], qf[t][1], z, 0, 0, 0);
                }
            }
            if (diag) {
                const int qloc = wave * 16 + c;
#pragma unroll
                for (int nb = 0; nb < 4; nb++) {
                    if (nb <= nbmax) {
                        const int kb = 32 * (nb >> 1) + 4 * (nb & 1) + 8 * quad;
#pragma unroll
                        for (int r = 0; r < 4; r++)
                            if (kb + r > qloc) sv[nb][r] = -INFINITY;
                    }
                }
            }

            unsigned int pd[4][2];
#pragma unroll
            for (int nb = 0; nb < 4; nb++) {
                if (nb <= nbmax) {
                    float p0 = __builtin_amdgcn_exp2f(sv[nb][0]);
                    float p1 = __builtin_amdgcn_exp2f(sv[nb][1]);
                    float p2 = __builtin_amdgcn_exp2f(sv[nb][2]);
                    float p3 = __builtin_amdgcn_exp2f(sv[nb][3]);
                    unsigned u0 = __float_as_uint(p0) + 0x8000u;
                    unsigned u1 = __float_as_uint(p1) + 0x8000u;
                    unsigned u2 = __float_as_uint(p2) + 0x8000u;
                    unsigned u3 = __float_as_uint(p3) + 0x8000u;
                    pd[nb][0] = (u0 >> 16) | (u1 & 0xffff0000u);
                    pd[nb][1] = (u2 >> 16) | (u3 & 0xffff0000u);
                } else {
                    pd[nb][0] = 0u; pd[nb][1] = 0u;
                }
            }

            bf16x8 ap0 = __builtin_bit_cast(bf16x8,
                (u32x4v){pd[0][0], pd[0][1], pd[1][0], pd[1][1]});
            bf16x8 ap1 = __builtin_bit_cast(bf16x8,
                (u32x4v){pd[2][0], pd[2][1], pd[3][0], pd[3][1]});

            Ol[t] = __builtin_amdgcn_mfma_f32_16x16x32_bf16(ap0, onesf, Ol[t], 0, 0, 0);
            if (doHi)
                Ol[t] = __builtin_amdgcn_mfma_f32_16x16x32_bf16(ap1, onesf, Ol[t], 0, 0, 0);

#pragma unroll
            for (int dd = 0; dd < 4; dd++) {
                const unsigned int* vrow = &Vt[(dd * 16 + c) * 36 + quad * 4];
                bf16x8 vb0 = __builtin_bit_cast(bf16x8, *(const u32x4v*)vrow);
                Oa[t][dd] = __builtin_amdgcn_mfma_f32_16x16x32_bf16(ap0, vb0, Oa[t][dd], 0, 0, 0);
                if (doHi) {
                    bf16x8 vb1 = __builtin_bit_cast(bf16x8, *(const u32x4v*)(vrow + 16));
                    Oa[t][dd] = __builtin_amdgcn_mfma_f32_16x16x32_bf16(ap1, vb1, Oa[t][dd], 0, 0, 0);
                }
            }
        }
    }

#pragma unroll
    for (int t = 0; t < 2; t++) {
        unsigned short* yrow =
            y + ((size_t)(b * T_ + q0s[t] + wave * 16)) * C_ + h * D_;
#pragma unroll
        for (int r = 0; r < 4; r++) {
            float inv = 1.f / Ol[t][r];
#pragma unroll
            for (int dd = 0; dd < 4; dd++)
                yrow[(size_t)(quad * 4 + r) * C_ + dd * 16 + c] = f2bf(Oa[t][dd][r] * inv);
        }
    }
}

extern "C" void kernel_launch(void* const* d_in, const int* in_sizes, int n_in,
                              void* d_out, int out_size, void* d_ws, size_t ws_size,
                              hipStream_t stream) {
    const float* x      = (const float*)d_in[0];
    const float* w_qkv  = (const float*)d_in[1];
    const float* b_qkv  = (const float*)d_in[2];
    const float* w_proj = (const float*)d_in[3];
    const float* b_proj = (const float*)d_in[4];
    float* out = (float*)d_out;

    unsigned short* wqT  = (unsigned short*)d_ws;                 // [2304][768]
    unsigned short* wpT  = wqT  + (size_t)3 * C_ * C_;            // [768][768]
    unsigned short* qkvb = wpT  + (size_t)C_ * C_;                // [8192][2304]
    unsigned short* yb   = qkvb + (size_t)B_ * T_ * 3 * C_;       // [8192][768]
    float*          bqs  = (float*)(yb + (size_t)B_ * T_ * C_);   // [2304]

    prep_w<<<577, 256, 0, stream>>>(w_qkv, b_qkv, w_proj, wqT, wpT, bqs);

    // qkv = x @ w_qkv + b_qkv  (fp32 A converted in staging; bf16 out)
    gemm_pipe<128, 1, 1><<<dim3(B_ * T_ / 128, 3 * C_ / 128), 256, 0, stream>>>(
        x, nullptr, wqT, bqs, qkvb, B_ * T_, 3 * C_, C_);

    // flash attention -> y (bf16)
    attn_mfma<<<8 * B_ * H_, 256, 0, stream>>>(qkvb, yb);

    // out = y @ w_proj + b_proj (bf16 A; fp32 out; 64x128 tile -> 768 blocks)
    gemm_pipe<64, 0, 0><<<dim3(B_ * T_ / 64, C_ / 128), 256, 0, stream>>>(
        nullptr, yb, wpT, b_proj, out, B_ * T_, C_, C_);
}

// Round 10
// 185.866 us; speedup vs baseline: 1.0288x; 1.0288x over previous
//
#include <hip/hip_runtime.h>
#include <math.h>

#define B_ 8
#define T_ 1024
#define C_ 768
#define H_ 12
#define D_ 64

typedef __bf16 bf16x8 __attribute__((ext_vector_type(8)));
typedef float  f32x4  __attribute__((ext_vector_type(4)));
typedef unsigned short us8 __attribute__((ext_vector_type(8)));
typedef unsigned int   u32x4v __attribute__((ext_vector_type(4)));

typedef __attribute__((address_space(3))) void lds_void;
typedef __attribute__((address_space(1))) const void glb_void;

#define KSC 0.18033688011112043f   // 0.125 * log2(e)

__device__ __forceinline__ unsigned short f2bf(float f) {
    unsigned int u = __float_as_uint(f);
    u += 0x7fffu + ((u >> 16) & 1u);
    return (unsigned short)(u >> 16);
}

// ---------------- merged prep: x->bf16, w transposes (+Q scale), bias -------
__global__ __launch_bounds__(256)
void prep_all(const float* __restrict__ x, const float* __restrict__ w_qkv,
              const float* __restrict__ b_qkv, const float* __restrict__ w_proj,
              unsigned short* __restrict__ xb, unsigned short* __restrict__ wqT,
              unsigned short* __restrict__ wpT, float* __restrict__ bqs) {
    __shared__ unsigned short Ts[64][65];
    const int id  = blockIdx.x;
    const int tid = threadIdx.x;
    if (id < 6144) {                       // x fp32 -> bf16, float4 granules
        int idx = id * 256 + tid;
        float4 v = ((const float4*)x)[idx];
        ushort4 o;
        o.x = f2bf(v.x); o.y = f2bf(v.y); o.z = f2bf(v.z); o.w = f2bf(v.w);
        ((ushort4*)xb)[idx] = o;
        return;
    }
    if (id >= 6720) {                      // bias with Q-scale
        int i = (id - 6720) * 256 + tid;
        if (i < 3 * C_) bqs[i] = b_qkv[i] * (i < C_ ? KSC : 1.f);
        return;
    }
    const float* W; unsigned short* Wt; int N, nlim, t2;
    if (id < 6576) { t2 = id - 6144; W = w_qkv;  Wt = wqT; N = 3 * C_; nlim = C_; }
    else           { t2 = id - 6576; W = w_proj; Wt = wpT; N = C_;     nlim = 0;  }
    const int ntiles = N / 64;
    const int n0 = (t2 % ntiles) * 64, k0 = (t2 / ntiles) * 64;
    for (int i = tid; i < 4096; i += 256) {
        int n = i & 63, k = i >> 6;
        float sc = (n0 + n < nlim) ? KSC : 1.f;
        Ts[n][k] = f2bf(W[(size_t)(k0 + k) * N + n0 + n] * sc);
    }
    __syncthreads();
    for (int i = tid; i < 4096; i += 256) {
        int k = i & 63, n = i >> 6;
        Wt[(size_t)(n0 + n) * 768 + k0 + k] = Ts[n][k];
    }
}

// ---------------- single-barrier full-dbuf bf16 MFMA GEMM -------------------
// TM x 128 tile, BK=64, A and B both double-buffered. One __syncthreads per
// round. Per round r: [barrier] -> load A(r+1) us8 regs -> issue B(r+1)
// global_load_lds into Bs[nb] -> compute round r (32 MFMA cover) ->
// ds_write A(r+1) into As[nb] (vmcnt waits only the 4 A loads, B stays in
// flight until next barrier -> full-round latency cover on both paths).
// LDS cells (16B): logical (row,kc) at linear row*8 + (kc ^ (row&7)) - the
// R7/R8 swizzle, measured 0 bank conflicts. No dtype conversion in-loop
// (A is bf16 from prep). blockIdx.x = M -> same-m blocks share XCD.
template<int TM, int OUT_BF16>
__global__ __launch_bounds__(256, 2)
void gemm_db(const unsigned short* __restrict__ A,
             const unsigned short* __restrict__ Bt,
             const float* __restrict__ bias,
             void* __restrict__ Cout, int M, int N, int K) {
    const int PA = TM / 32;     // A cells per thread (TM*8/256)
    const int MI = TM / 32;     // m-frags per wave
    __shared__ __align__(16) unsigned short As[2][TM * 64];
    __shared__ __align__(16) unsigned short Bs[2][8192];

    const int tid  = threadIdx.x;
    const int lane = tid & 63;
    const int c    = lane & 15;
    const int quad = lane >> 4;
    const int wave = tid >> 6;
    const int wm   = (wave >> 1) * (TM / 2);
    const int wn   = (wave & 1) * 64;
    const int bm   = blockIdx.x * TM;
    const int bn   = blockIdx.y * 128;

    // A: thread owns linear cells Lp (contiguous ds_write); source cell is
    // the swizzled logical cell. B: global_load_lds with pre-swizzled source.
    const unsigned short* aS[PA];
    int wA[PA];
#pragma unroll
    for (int p = 0; p < PA; p++) {
        const int Lp = p * 256 + tid;
        const int L  = Lp ^ ((Lp >> 3) & 7);
        aS[p] = A + (size_t)(bm + (L >> 3)) * K + (L & 7) * 8;
        wA[p] = Lp * 8;
    }
    const unsigned short* bS[4];
#pragma unroll
    for (int p = 0; p < 4; p++) {
        const int Lp = p * 256 + tid;
        const int L  = Lp ^ ((Lp >> 3) & 7);
        bS[p] = Bt + (size_t)(bn + (L >> 3)) * K + (L & 7) * 8;
    }
    const int wb = (tid & 0xC0) * 8;

    int aoff[MI][2], boff[4][2];
#pragma unroll
    for (int i = 0; i < MI; i++)
#pragma unroll
        for (int ks = 0; ks < 2; ks++) {
            const int kcA = (ks * 4 + quad) ^ (c & 7);
            aoff[i][ks] = ((wm + i * 16 + c) * 8 + kcA) * 8;
        }
#pragma unroll
    for (int j = 0; j < 4; j++)
#pragma unroll
        for (int ks = 0; ks < 2; ks++) {
            const int kcA = (ks * 4 + quad) ^ (c & 7);
            boff[j][ks] = ((wn + j * 16 + c) * 8 + kcA) * 8;
        }

    us8 aR[PA];
    f32x4 acc[MI][4];
#pragma unroll
    for (int i = 0; i < MI; i++)
#pragma unroll
        for (int j = 0; j < 4; j++) acc[i][j] = (f32x4){0.f, 0.f, 0.f, 0.f};

    // prologue: stage round 0 into buffer 0 (latency exposed once)
#pragma unroll
    for (int p = 0; p < PA; p++) { aR[p] = *(const us8*)aS[p]; aS[p] += 64; }
#pragma unroll
    for (int p = 0; p < 4; p++) {
        __builtin_amdgcn_global_load_lds((glb_void*)bS[p],
            (lds_void*)(&Bs[0][0] + p * 2048 + wb), 16, 0, 0);
        bS[p] += 64;
    }
#pragma unroll
    for (int p = 0; p < PA; p++) *(us8*)&As[0][wA[p]] = aR[p];

    const int R = K >> 6;
    for (int r = 0; r < R; r++) {
        __syncthreads();   // round-r staging visible; drains B(r) DMAs
        const int bb = r & 1, nb = bb ^ 1;
        if (r + 1 < R) {   // prefetch r+1: A regs first, then B DMA (FIFO)
#pragma unroll
            for (int p = 0; p < PA; p++) { aR[p] = *(const us8*)aS[p]; aS[p] += 64; }
#pragma unroll
            for (int p = 0; p < 4; p++) {
                __builtin_amdgcn_global_load_lds((glb_void*)bS[p],
                    (lds_void*)(&Bs[nb][0] + p * 2048 + wb), 16, 0, 0);
                bS[p] += 64;
            }
        }

#pragma unroll
        for (int ks = 0; ks < 2; ks++) {
            bf16x8 af[MI], bfr[4];
#pragma unroll
            for (int i = 0; i < MI; i++)
                af[i] = __builtin_bit_cast(bf16x8, *(const us8*)&As[bb][aoff[i][ks]]);
#pragma unroll
            for (int j = 0; j < 4; j++)
                bfr[j] = __builtin_bit_cast(bf16x8, *(const us8*)&Bs[bb][boff[j][ks]]);
#pragma unroll
            for (int i = 0; i < MI; i++)
#pragma unroll
                for (int j = 0; j < 4; j++)
                    acc[i][j] = __builtin_amdgcn_mfma_f32_16x16x32_bf16(af[i], bfr[j], acc[i][j], 0, 0, 0);
        }

        if (r + 1 < R) {   // ds_write A(r+1): waits only A's vmcnt
#pragma unroll
            for (int p = 0; p < PA; p++) *(us8*)&As[nb][wA[p]] = aR[p];
        }
    }

    float bs[4];
#pragma unroll
    for (int j = 0; j < 4; j++) bs[j] = bias[bn + wn + j * 16 + c];
#pragma unroll
    for (int i = 0; i < MI; i++) {
        const int gm = bm + wm + i * 16 + quad * 4;
#pragma unroll
        for (int r = 0; r < 4; r++) {
            const size_t ro = (size_t)(gm + r) * N;
#pragma unroll
            for (int j = 0; j < 4; j++) {
                const float v = acc[i][j][r] + bs[j];
                const int gn = bn + wn + j * 16 + c;
                if (OUT_BF16) ((unsigned short*)Cout)[ro + gn] = f2bf(v);
                else          ((float*)Cout)[ro + gn] = v;
            }
        }
    }
}

// key k -> permuted LDS row, chosen so S^T output lands in PV A-frag layout
__device__ __forceinline__ int sigmaK(int k) {
    return 16 * (2 * (k >> 5) + ((k >> 2) & 1)) + 4 * ((k >> 3) & 3) + (k & 3);
}

// ---------------- flash attention: S^T trick, in-register P -----------------
__global__ __launch_bounds__(256, 3)
void attn_mfma(const unsigned short* __restrict__ qkv, unsigned short* __restrict__ y) {
    __shared__ __align__(16) unsigned short Ks[64 * 72];
    __shared__ __align__(16) unsigned int   Vt[64 * 36];

    const int tid  = threadIdx.x;
    const int wave = tid >> 6;
    const int lane = tid & 63;
    const int c    = lane & 15;
    const int quad = lane >> 4;

    const int id = blockIdx.x;
    const int p  = (id >> 3) & 7;
    const int bh = (id >> 6) * 8 + (id & 7);
    const int b  = bh / H_;
    const int h  = bh - b * H_;

    const int qts[2] = {p, 15 - p};
    const int q0s[2] = {p * 64, (15 - p) * 64};

    const int RS = 3 * C_;
    const unsigned short* kbase = qkv + (size_t)b * T_ * RS + C_ + h * D_;
    const unsigned short* vbase = qkv + (size_t)b * T_ * RS + 2 * C_ + h * D_;

    const u32x4v onesu = {0x3F803F80u, 0x3F803F80u, 0x3F803F80u, 0x3F803F80u};
    const bf16x8 onesf = __builtin_bit_cast(bf16x8, onesu);

    bf16x8 qf[2][2];
#pragma unroll
    for (int t = 0; t < 2; t++) {
        const unsigned short* qrow =
            qkv + ((size_t)(b * T_ + q0s[t] + wave * 16 + c)) * RS + h * D_ + quad * 8;
        qf[t][0] = __builtin_bit_cast(bf16x8, *(const us8*)qrow);
        qf[t][1] = __builtin_bit_cast(bf16x8, *(const us8*)(qrow + 32));
    }

    const int kr0 = tid >> 3, kc0 = tid & 7;
    const int sK0 = sigmaK(kr0) * 72 + kc0 * 8;
    const int sK1 = sigmaK(kr0 + 32) * 72 + kc0 * 8;
    const int dg  = tid >> 4, kp0 = tid & 15;

    us8 kA, kB;
    ushort4 vA0, vB0, vA1, vB1;
    {
        kA = *(const us8*)(kbase + (size_t)kr0 * RS + kc0 * 8);
        kB = *(const us8*)(kbase + (size_t)(kr0 + 32) * RS + kc0 * 8);
        const unsigned short* p0 = vbase + (size_t)(2 * kp0) * RS + dg * 4;
        vA0 = *(const ushort4*)p0;  vB0 = *(const ushort4*)(p0 + RS);
        const unsigned short* p1 = vbase + (size_t)(2 * (kp0 + 16)) * RS + dg * 4;
        vA1 = *(const ushort4*)p1;  vB1 = *(const ushort4*)(p1 + RS);
    }

    f32x4 Oa[2][4];
    f32x4 Ol[2];
#pragma unroll
    for (int t = 0; t < 2; t++) {
        Ol[t] = (f32x4){0.f, 0.f, 0.f, 0.f};
#pragma unroll
        for (int d = 0; d < 4; d++) Oa[t][d] = (f32x4){0.f, 0.f, 0.f, 0.f};
    }

    const int ktEnd = qts[1];
    for (int kt = 0; kt <= ktEnd; kt++) {
        __syncthreads();
        *(us8*)&Ks[sK0] = kA;
        *(us8*)&Ks[sK1] = kB;
        {
            unsigned int* v0 = &Vt[(dg * 4) * 36 + kp0];
            v0[0]   = vA0.x | ((unsigned)vB0.x << 16);
            v0[36]  = vA0.y | ((unsigned)vB0.y << 16);
            v0[72]  = vA0.z | ((unsigned)vB0.z << 16);
            v0[108] = vA0.w | ((unsigned)vB0.w << 16);
            unsigned int* v1 = v0 + 16;
            v1[0]   = vA1.x | ((unsigned)vB1.x << 16);
            v1[36]  = vA1.y | ((unsigned)vB1.y << 16);
            v1[72]  = vA1.z | ((unsigned)vB1.z << 16);
            v1[108] = vA1.w | ((unsigned)vB1.w << 16);
        }
        __syncthreads();

        if (kt < ktEnd) {
            const unsigned short* kp = kbase + (size_t)((kt + 1) * 64) * RS;
            kA = *(const us8*)(kp + (size_t)kr0 * RS + kc0 * 8);
            kB = *(const us8*)(kp + (size_t)(kr0 + 32) * RS + kc0 * 8);
            const unsigned short* vp = vbase + (size_t)((kt + 1) * 64) * RS;
            const unsigned short* p0 = vp + (size_t)(2 * kp0) * RS + dg * 4;
            vA0 = *(const ushort4*)p0;  vB0 = *(const ushort4*)(p0 + RS);
            const unsigned short* p1 = vp + (size_t)(2 * (kp0 + 16)) * RS + dg * 4;
            vA1 = *(const ushort4*)p1;  vB1 = *(const ushort4*)(p1 + RS);
        }

        bf16x8 kf[4][2];
#pragma unroll
        for (int nb = 0; nb < 4; nb++) {
#pragma unroll
            for (int ks = 0; ks < 2; ks++)
                kf[nb][ks] = __builtin_bit_cast(bf16x8,
                    *(const us8*)&Ks[(nb * 16 + c) * 72 + quad * 8 + ks * 32]);
        }

#pragma unroll
        for (int t = 0; t < 2; t++) {
            if (kt > qts[t]) continue;
            const bool diag = (kt == qts[t]);
            const bool doHi = !diag || (wave >= 2);
            const int nbmax = diag ? ((wave >= 2) ? 3 : 1) : 3;

            f32x4 sv[4];
#pragma unroll
            for (int nb = 0; nb < 4; nb++) {
                if (nb <= nbmax) {
                    f32x4 z = (f32x4){0.f, 0.f, 0.f, 0.f};
                    z = __builtin_amdgcn_mfma_f32_16x16x32_bf16(kf[nb][0], qf[t][0], z, 0, 0, 0);
                    sv[nb] = __builtin_amdgcn_mfma_f32_16x16x32_bf16(kf[nb][1], qf[t][1], z, 0, 0, 0);
                }
            }
            if (diag) {
                const int qloc = wave * 16 + c;
#pragma unroll
                for (int nb = 0; nb < 4; nb++) {
                    if (nb <= nbmax) {
                        const int kb = 32 * (nb >> 1) + 4 * (nb & 1) + 8 * quad;
#pragma unroll
                        for (int r = 0; r < 4; r++)
                            if (kb + r > qloc) sv[nb][r] = -INFINITY;
                    }
                }
            }

            unsigned int pd[4][2];
#pragma unroll
            for (int nb = 0; nb < 4; nb++) {
                if (nb <= nbmax) {
                    float p0 = __builtin_amdgcn_exp2f(sv[nb][0]);
                    float p1 = __builtin_amdgcn_exp2f(sv[nb][1]);
                    float p2 = __builtin_amdgcn_exp2f(sv[nb][2]);
                    float p3 = __builtin_amdgcn_exp2f(sv[nb][3]);
                    unsigned u0 = __float_as_uint(p0) + 0x8000u;
                    unsigned u1 = __float_as_uint(p1) + 0x8000u;
                    unsigned u2 = __float_as_uint(p2) + 0x8000u;
                    unsigned u3 = __float_as_uint(p3) + 0x8000u;
                    pd[nb][0] = (u0 >> 16) | (u1 & 0xffff0000u);
                    pd[nb][1] = (u2 >> 16) | (u3 & 0xffff0000u);
                } else {
                    pd[nb][0] = 0u; pd[nb][1] = 0u;
                }
            }

            bf16x8 ap0 = __builtin_bit_cast(bf16x8,
                (u32x4v){pd[0][0], pd[0][1], pd[1][0], pd[1][1]});
            bf16x8 ap1 = __builtin_bit_cast(bf16x8,
                (u32x4v){pd[2][0], pd[2][1], pd[3][0], pd[3][1]});

            Ol[t] = __builtin_amdgcn_mfma_f32_16x16x32_bf16(ap0, onesf, Ol[t], 0, 0, 0);
            if (doHi)
                Ol[t] = __builtin_amdgcn_mfma_f32_16x16x32_bf16(ap1, onesf, Ol[t], 0, 0, 0);

#pragma unroll
            for (int dd = 0; dd < 4; dd++) {
                const unsigned int* vrow = &Vt[(dd * 16 + c) * 36 + quad * 4];
                bf16x8 vb0 = __builtin_bit_cast(bf16x8, *(const u32x4v*)vrow);
                Oa[t][dd] = __builtin_amdgcn_mfma_f32_16x16x32_bf16(ap0, vb0, Oa[t][dd], 0, 0, 0);
                if (doHi) {
                    bf16x8 vb1 = __builtin_bit_cast(bf16x8, *(const u32x4v*)(vrow + 16));
                    Oa[t][dd] = __builtin_amdgcn_mfma_f32_16x16x32_bf16(ap1, vb1, Oa[t][dd], 0, 0, 0);
                }
            }
        }
    }

#pragma unroll
    for (int t = 0; t < 2; t++) {
        unsigned short* yrow =
            y + ((size_t)(b * T_ + q0s[t] + wave * 16)) * C_ + h * D_;
#pragma unroll
        for (int r = 0; r < 4; r++) {
            float inv = 1.f / Ol[t][r];
#pragma unroll
            for (int dd = 0; dd < 4; dd++)
                yrow[(size_t)(quad * 4 + r) * C_ + dd * 16 + c] = f2bf(Oa[t][dd][r] * inv);
        }
    }
}

extern "C" void kernel_launch(void* const* d_in, const int* in_sizes, int n_in,
                              void* d_out, int out_size, void* d_ws, size_t ws_size,
                              hipStream_t stream) {
    const float* x      = (const float*)d_in[0];
    const float* w_qkv  = (const float*)d_in[1];
    const float* b_qkv  = (const float*)d_in[2];
    const float* w_proj = (const float*)d_in[3];
    const float* b_proj = (const float*)d_in[4];
    float* out = (float*)d_out;

    unsigned short* xb   = (unsigned short*)d_ws;                 // [8192][768]
    unsigned short* wqT  = xb   + (size_t)B_ * T_ * C_;           // [2304][768]
    unsigned short* wpT  = wqT  + (size_t)3 * C_ * C_;            // [768][768]
    unsigned short* qkvb = wpT  + (size_t)C_ * C_;                // [8192][2304]
    unsigned short* yb   = qkvb + (size_t)B_ * T_ * 3 * C_;       // [8192][768]
    float*          bqs  = (float*)(yb + (size_t)B_ * T_ * C_);   // [2304]

    // merged prep: 6144 x-convert + 432 + 144 transpose + 9 bias
    prep_all<<<6729, 256, 0, stream>>>(x, w_qkv, b_qkv, w_proj, xb, wqT, wpT, bqs);

    // qkv = x @ w_qkv + b_qkv  (bf16 A; bf16 out). blockIdx.x = M.
    gemm_db<128, 1><<<dim3(B_ * T_ / 128, 3 * C_ / 128), 256, 0, stream>>>(
        xb, wqT, bqs, qkvb, B_ * T_, 3 * C_, C_);

    // flash attention -> y (bf16)
    attn_mfma<<<8 * B_ * H_, 256, 0, stream>>>(qkvb, yb);

    // out = y @ w_proj + b_proj (bf16 A; fp32 out; 64x128 tile -> 768 blocks)
    gemm_db<64, 0><<<dim3(B_ * T_ / 64, C_ / 128), 256, 0, stream>>>(
        yb, wpT, b_proj, out, B_ * T_, C_, C_);
}